// Round 8
// baseline (141.597 us; speedup 1.0000x reference)
//
#include <hip/hip_runtime.h>

// Problem constants (match reference)
#define NE_   1000           // number of energies (evl)
#define RN_   10000          // number of radial grid points
#define NI_   (RN_ - 1)      // 9999 integration intervals
#define CPB_  8              // channels per block
#define TPC_  64             // threads (segments) per channel
#define LSEG_ ((NI_ + TPC_ - 1) / TPC_)   // 157 intervals per segment

__device__ __forceinline__ float rcpf(float x) { return __builtin_amdgcn_rcpf(x); }

// Substep schedule (p < 64 only). RK4 local error ~ (w*h)^5/120 with
// w = sqrt(2/t + |e|): p<16: S=4, p<64: S=2, else S=1.
__device__ __forceinline__ void substeps_for(int p, int& S, float& invS) {
    if (p < 16)      { S = 4; invS = 0.25f; }
    else if (p < 64) { S = 2; invS = 0.5f;  }
    else             { S = 1; invS = 1.0f;  }
}

// One classic RK4 step for NV independent solutions of a'=b, b'=q(t)a.
template <int NV>
__device__ __forceinline__ void rk4_step(float q1, float q2, float q3,
                                         float h2, float h, float h6,
                                         float a[NV], float b[NV]) {
#pragma unroll
    for (int v = 0; v < NV; ++v) {
        const float ya = a[v], yb = b[v];
        const float k1a = yb;                const float k1b = q1 * ya;
        const float y2a = fmaf(h2, k1a, ya); const float y2b = fmaf(h2, k1b, yb);
        const float k2a = y2b;               const float k2b = q2 * y2a;
        const float y3a = fmaf(h2, k2a, ya); const float y3b = fmaf(h2, k2b, yb);
        const float k3a = y3b;               const float k3b = q2 * y3a;
        const float y4a = fmaf(h,  k3a, ya); const float y4b = fmaf(h,  k3b, yb);
        const float k4a = y4b;               const float k4b = q3 * y4a;
        a[v] = fmaf(h6, fmaf(2.0f, k2a + k3a, k1a + k4a), ya);
        b[v] = fmaf(h6, fmaf(2.0f, k2b + k3b, k1b + k4b), yb);
    }
}

// General (sub-stepped) interval advance — used only for p < 64.
template <int NV>
__device__ __forceinline__ void advance_interval(float ta, float tb, float e,
                                                 int S, float invS,
                                                 float a[NV], float b[NV]) {
    const float hs = (tb - ta) * invS;
    const float h2 = 0.5f * hs;
    const float h6 = hs * (1.0f / 6.0f);
    for (int j = 0; j < S; ++j) {
        const float t0 = ta + hs * (float)j;
        const float q1 = fmaf(-2.0f, rcpf(t0),      -e);
        const float q2 = fmaf(-2.0f, rcpf(t0 + h2), -e);
        const float q3 = fmaf(-2.0f, rcpf(t0 + hs), -e);
        rk4_step<NV>(q1, q2, q3, h2, hs, h6, a, b);
    }
}

// Fully fused solver: one block owns CPB_ channels over the WHOLE time range.
//   sweep 1: thread (ei, j) integrates the 2x2 basis over segment j -> LDS
//   LDS scan: 64 composites chained serially per channel (cheap)
//   sweep 2: thread re-integrates the vector ODE from its segment-start
//            state, writing [u, u'] at every grid point (coalesced 64B/p).
// No workspace, no intermediate kernels.
__global__ __launch_bounds__(CPB_ * TPC_) void
k_fused(const float* __restrict__ evl, const float* __restrict__ t,
        float2* __restrict__ out) {
    __shared__ float4 lm[CPB_][TPC_];   // segment composites {m00,m10,m01,m11}
    __shared__ float2 ly[CPB_][TPC_];   // segment-start states

    const int tid = threadIdx.x;
    const int eil = tid & (CPB_ - 1);
    const int j   = tid >> 3;                 // segment index 0..63
    const int ei  = blockIdx.x * CPB_ + eil;  // 125*8 == NE_, always in range

    const float e    = evl[ei];
    const float t0g  = t[0];
    const float step = (t[RN_ - 1] - t0g) * (1.0f / (float)NI_);
    const int p0 = j * LSEG_;
    const int p1 = min(p0 + LSEG_, NI_);

    // ---- sweep 1: basis propagator over [p0, p1) ----
    // Fast region uses DOUBLE steps (h = 2*grid step): phase error
    // ~ Phi*(wh)^4/120 ~ 4.5e-5 relative — far under the 2%-of-peak threshold.
    float a2[2] = {1.0f, 0.0f};
    float b2[2] = {0.0f, 1.0f};
    int p = p0;
    while (p < p1 && p < 64) {                 // only j==0 enters here
        const float ta = fmaf((float)p,       step, t0g);
        const float tb = fmaf((float)(p + 1), step, t0g);
        int S; float invS; substeps_for(p, S, invS);
        advance_interval<2>(ta, tb, e, S, invS, a2, b2);
        ++p;
    }
    if (p < p1) {
        float tcur = fmaf((float)p, step, t0g);
        float qcur = fmaf(-2.0f, rcpf(tcur), -e);
        while (p + 2 <= p1) {                  // double steps
            const float tmid  = fmaf((float)(p + 1), step, t0g);
            const float tnext = fmaf((float)(p + 2), step, t0g);
            const float h  = tnext - tcur;
            const float h2 = 0.5f * h;
            const float h6 = h * (1.0f / 6.0f);
            const float qmid  = fmaf(-2.0f, rcpf(tmid),  -e);
            const float qnext = fmaf(-2.0f, rcpf(tnext), -e);
            rk4_step<2>(qcur, qmid, qnext, h2, h, h6, a2, b2);
            tcur = tnext; qcur = qnext; p += 2;
        }
        if (p < p1) {                          // odd tail: one single step
            const float tmid  = fmaf((float)p + 0.5f, step, t0g);
            const float tnext = fmaf((float)(p + 1),  step, t0g);
            const float h  = tnext - tcur;
            const float h2 = 0.5f * h;
            const float h6 = h * (1.0f / 6.0f);
            const float qmid  = fmaf(-2.0f, rcpf(tmid),  -e);
            const float qnext = fmaf(-2.0f, rcpf(tnext), -e);
            rk4_step<2>(qcur, qmid, qnext, h2, h, h6, a2, b2);
        }
    }
    lm[eil][j] = make_float4(a2[0], b2[0], a2[1], b2[1]);
    __syncthreads();

    // ---- LDS scan: chain the 64 segment composites per channel ----
    if (j == 0) {
        float ya = 0.0f, yb = 1.0f;            // y(t[0]) = [0, 1]
        for (int k = 0; k < TPC_; ++k) {
            ly[eil][k] = make_float2(ya, yb);
            const float4 m = lm[eil][k];
            const float na = fmaf(m.x, ya, m.z * yb);
            const float nb = fmaf(m.y, ya, m.w * yb);
            ya = na; yb = nb;
        }
    }
    __syncthreads();
    const float2 y0 = ly[eil][j];

    // ---- sweep 2: vector ODE from segment-start state, store every point ----
    float a1[1] = {y0.x};
    float b1[1] = {y0.y};
    if (j == 0) out[ei] = make_float2(0.0f, 1.0f);   // IC at t[0]
    p = p0;
    while (p < p1 && p < 64) {                 // only j==0 enters here
        const float ta = fmaf((float)p,       step, t0g);
        const float tb = fmaf((float)(p + 1), step, t0g);
        int S; float invS; substeps_for(p, S, invS);
        advance_interval<1>(ta, tb, e, S, invS, a1, b1);
        out[(size_t)(p + 1) * NE_ + ei] = make_float2(a1[0], b1[0]);
        ++p;
    }
    if (p < p1) {
        float tcur = fmaf((float)p, step, t0g);
        float qcur = fmaf(-2.0f, rcpf(tcur), -e);
        for (; p < p1; ++p) {                  // single steps, q reused
            const float tmid  = fmaf((float)p + 0.5f, step, t0g);
            const float tnext = fmaf((float)(p + 1),  step, t0g);
            const float h  = tnext - tcur;
            const float h2 = 0.5f * h;
            const float h6 = h * (1.0f / 6.0f);
            const float qmid  = fmaf(-2.0f, rcpf(tmid),  -e);
            const float qnext = fmaf(-2.0f, rcpf(tnext), -e);
            rk4_step<1>(qcur, qmid, qnext, h2, h, h6, a1, b1);
            out[(size_t)(p + 1) * NE_ + ei] = make_float2(a1[0], b1[0]);
            tcur = tnext; qcur = qnext;
        }
    }
}

extern "C" void kernel_launch(void* const* d_in, const int* in_sizes, int n_in,
                              void* d_out, int out_size, void* d_ws, size_t ws_size,
                              hipStream_t stream) {
    const float* evl = (const float*)d_in[0];   // NE_ energies
    const float* t   = (const float*)d_in[1];   // RN_ radial grid
    float2* out = (float2*)d_out;               // [RN_][NE_] of {rad, rad_d}
    (void)d_ws; (void)ws_size;

    // 125 blocks x 512 threads: block = 8 channels x 64 segments
    k_fused<<<NE_ / CPB_, CPB_ * TPC_, 0, stream>>>(evl, t, out);
}

// Round 9
// 124.528 us; speedup vs baseline: 1.1371x; 1.1371x over previous
//
#include <hip/hip_runtime.h>

// Problem constants (match reference)
#define NE_    1000          // number of energies (evl)
#define RN_    10000         // number of radial grid points
#define NI_    (RN_ - 1)     // 9999 integration intervals
#define CH_    10            // intervals per chunk
#define NCH_   1000          // real chunks (chunk 999 ragged: 9 intervals)
#define SLOTS_ 64            // slots per channel (threads per channel in K1)
#define CPS_   16            // chunks per slot (64*16=1024 virtual chunks)
#define CPB_   8             // channels per block in K1

__device__ __forceinline__ float rcpf(float x) { return __builtin_amdgcn_rcpf(x); }

// Substep schedule (p < 64 only). RK4 local error ~ (w*h)^5/120.
__device__ __forceinline__ void substeps_for(int p, int& S, float& invS) {
    if (p < 16)      { S = 4; invS = 0.25f; }
    else if (p < 64) { S = 2; invS = 0.5f;  }
    else             { S = 1; invS = 1.0f;  }
}

// One classic RK4 step for NV independent solutions of a'=b, b'=q(t)a.
template <int NV>
__device__ __forceinline__ void rk4_step(float q1, float q2, float q3,
                                         float h2, float h, float h6,
                                         float a[NV], float b[NV]) {
#pragma unroll
    for (int v = 0; v < NV; ++v) {
        const float ya = a[v], yb = b[v];
        const float k1a = yb;                const float k1b = q1 * ya;
        const float y2a = fmaf(h2, k1a, ya); const float y2b = fmaf(h2, k1b, yb);
        const float k2a = y2b;               const float k2b = q2 * y2a;
        const float y3a = fmaf(h2, k2a, ya); const float y3b = fmaf(h2, k2b, yb);
        const float k3a = y3b;               const float k3b = q2 * y3a;
        const float y4a = fmaf(h,  k3a, ya); const float y4b = fmaf(h,  k3b, yb);
        const float k4a = y4b;               const float k4b = q3 * y4a;
        a[v] = fmaf(h6, fmaf(2.0f, k2a + k3a, k1a + k4a), ya);
        b[v] = fmaf(h6, fmaf(2.0f, k2b + k3b, k1b + k4b), yb);
    }
}

// General (sub-stepped) interval advance — p < 64 and ragged tail only.
template <int NV>
__device__ __forceinline__ void advance_interval(float ta, float tb, float e,
                                                 int S, float invS,
                                                 float a[NV], float b[NV]) {
    const float hs = (tb - ta) * invS;
    const float h2 = 0.5f * hs;
    const float h6 = hs * (1.0f / 6.0f);
    for (int j = 0; j < S; ++j) {
        const float t0 = ta + hs * (float)j;
        const float q1 = fmaf(-2.0f, rcpf(t0),      -e);
        const float q2 = fmaf(-2.0f, rcpf(t0 + h2), -e);
        const float q3 = fmaf(-2.0f, rcpf(t0 + hs), -e);
        rk4_step<NV>(q1, q2, q3, h2, hs, h6, a, b);
    }
}

// 2x2 matmul, column-major float4 {m00, m10, m01, m11}. Returns B*A.
__device__ __forceinline__ float4 mmul(float4 B, float4 A) {
    float4 r;
    r.x = fmaf(B.x, A.x, B.z * A.y);
    r.y = fmaf(B.y, A.x, B.w * A.y);
    r.z = fmaf(B.x, A.z, B.z * A.w);
    r.w = fmaf(B.y, A.z, B.w * A.w);
    return r;
}

// K1: fused propagator + scan. Block = CPB_ channels x SLOTS_ slot-threads.
// Each thread builds its CPS_ chunk matrices in registers (no global M!),
// composes the slot, LDS-scan chains 64 slot composites per channel, then
// replays the register matrices to emit all chunk-start states Yst[c][ei].
__global__ __launch_bounds__(CPB_ * SLOTS_) void
k_scanfused(const float* __restrict__ evl, const float* __restrict__ t,
            float2* __restrict__ Yst) {
    __shared__ float4 lm[CPB_][SLOTS_];   // slot composites
    __shared__ float2 ly[CPB_][SLOTS_];   // slot-start states

    const int tid  = threadIdx.x;
    const int eil  = tid & (CPB_ - 1);
    const int slot = tid >> 3;
    const int ei   = blockIdx.x * CPB_ + eil;   // 125*8 == NE_

    const float e    = evl[ei];
    const float t0g  = t[0];
    const float step = (t[RN_ - 1] - t0g) * (1.0f / (float)NI_);

    // ---- build CPS_ chunk matrices (basis columns) in registers ----
    float4 Mc[CPS_];
#pragma unroll
    for (int i = 0; i < CPS_; ++i) {
        const int c  = slot * CPS_ + i;
        const int p0 = c * CH_;
        const int p1 = min(p0 + CH_, NI_);
        float a2[2] = {1.0f, 0.0f};
        float b2[2] = {0.0f, 1.0f};
        if (p0 < NI_) {
            if (p0 >= 64 && p1 == p0 + CH_) {
                // fast: 5 DOUBLE RK4 steps (h = 2*grid step), q reused
                float tcur = fmaf((float)p0, step, t0g);
                float qcur = fmaf(-2.0f, rcpf(tcur), -e);
#pragma unroll
                for (int k = 0; k < CH_ / 2; ++k) {
                    const float pf    = (float)(p0 + 2 * k);
                    const float tmid  = fmaf(pf + 1.0f, step, t0g);
                    const float tnext = fmaf(pf + 2.0f, step, t0g);
                    const float h  = tnext - tcur;
                    const float h2 = 0.5f * h;
                    const float h6 = h * (1.0f / 6.0f);
                    const float qmid  = fmaf(-2.0f, rcpf(tmid),  -e);
                    const float qnext = fmaf(-2.0f, rcpf(tnext), -e);
                    rk4_step<2>(qcur, qmid, qnext, h2, h, h6, a2, b2);
                    tcur = tnext; qcur = qnext;
                }
            } else {
                // general: per-interval with substeps (p<64) / ragged tail
                for (int p = p0; p < p1; ++p) {
                    const float ta = fmaf((float)p,       step, t0g);
                    const float tb = fmaf((float)(p + 1), step, t0g);
                    int S; float invS; substeps_for(p, S, invS);
                    advance_interval<2>(ta, tb, e, S, invS, a2, b2);
                }
            }
        }
        Mc[i] = make_float4(a2[0], b2[0], a2[1], b2[1]);
    }

    // ---- slot composite: Mc[15] * ... * Mc[0] ----
    float4 C = Mc[0];
#pragma unroll
    for (int i = 1; i < CPS_; ++i) C = mmul(Mc[i], C);
    lm[eil][slot] = C;
    __syncthreads();

    // ---- per-channel serial chain over 64 slot composites (8 threads) ----
    if (slot == 0) {
        float ya = 0.0f, yb = 1.0f;          // y(t[0]) = [0, 1]
#pragma unroll 8
        for (int k = 0; k < SLOTS_; ++k) {
            ly[eil][k] = make_float2(ya, yb);
            const float4 m = lm[eil][k];
            const float na = fmaf(m.x, ya, m.z * yb);
            const float nb = fmaf(m.y, ya, m.w * yb);
            ya = na; yb = nb;
        }
    }
    __syncthreads();

    // ---- replay register matrices to emit chunk-start states ----
    const float2 y0 = ly[eil][slot];
    float ya = y0.x, yb = y0.y;
#pragma unroll
    for (int i = 0; i < CPS_; ++i) {
        const int c = slot * CPS_ + i;
        if (c < NCH_)
            Yst[(size_t)c * NE_ + ei] = make_float2(ya, yb);
        const float4 m = Mc[i];
        const float na = fmaf(m.x, ya, m.z * yb);
        const float nb = fmaf(m.y, ya, m.w * yb);
        ya = na; yb = nb;
    }
}

// K2: per (chunk, energy): re-integrate from chunk-start state, one RK4 per
// interval (2 rcp via q reuse), writing [u, u'] at each grid point.
// 1M threads; lane-consecutive ei -> fully coalesced 512B stores. (r5-proven)
__global__ void k_out(const float* __restrict__ evl, const float* __restrict__ t,
                      const float2* __restrict__ Yst, float2* __restrict__ out) {
    const int tid = blockIdx.x * blockDim.x + threadIdx.x;
    if (tid >= NE_ * NCH_) return;
    const int ei = tid % NE_;
    const int c  = tid / NE_;
    const float e    = evl[ei];
    const float t0g  = t[0];
    const float step = (t[RN_ - 1] - t0g) * (1.0f / (float)NI_);
    const int p0 = c * CH_;
    const int p1 = min(p0 + CH_, NI_);
    const float2 y0 = Yst[tid];
    float a[1] = {y0.x};
    float b[1] = {y0.y};
    if (c == 0) out[ei] = make_float2(0.0f, 1.0f);   // IC at t[0]
    if (p0 >= 64 && p0 + CH_ == p1) {
        float tcur = fmaf((float)p0, step, t0g);
        float qcur = fmaf(-2.0f, rcpf(tcur), -e);
#pragma unroll
        for (int k = 0; k < CH_; ++k) {
            const float pf    = (float)(p0 + k);
            const float tmid  = fmaf(pf + 0.5f, step, t0g);
            const float tnext = fmaf(pf + 1.0f, step, t0g);
            const float h  = tnext - tcur;
            const float h2 = 0.5f * h;
            const float h6 = h * (1.0f / 6.0f);
            const float qmid  = fmaf(-2.0f, rcpf(tmid),  -e);
            const float qnext = fmaf(-2.0f, rcpf(tnext), -e);
            rk4_step<1>(qcur, qmid, qnext, h2, h, h6, a, b);
            out[(size_t)(p0 + k + 1) * NE_ + ei] = make_float2(a[0], b[0]);
            tcur = tnext; qcur = qnext;
        }
    } else {
        for (int p = p0; p < p1; ++p) {
            const float ta = fmaf((float)p,       step, t0g);
            const float tb = fmaf((float)(p + 1), step, t0g);
            int S; float invS; substeps_for(p, S, invS);
            advance_interval<1>(ta, tb, e, S, invS, a, b);
            out[(size_t)(p + 1) * NE_ + ei] = make_float2(a[0], b[0]);
        }
    }
}

// Fallback: fully serial per channel (only if ws_size is tiny).
__global__ void k_serial(const float* __restrict__ evl, const float* __restrict__ t,
                         float2* __restrict__ out) {
    const int ei = blockIdx.x * blockDim.x + threadIdx.x;
    if (ei >= NE_) return;
    const float e    = evl[ei];
    const float t0g  = t[0];
    const float step = (t[RN_ - 1] - t0g) * (1.0f / (float)NI_);
    float a[1] = {0.0f};
    float b[1] = {1.0f};
    out[ei] = make_float2(0.0f, 1.0f);
    for (int p = 0; p < NI_; ++p) {
        const float ta = fmaf((float)p,       step, t0g);
        const float tb = fmaf((float)(p + 1), step, t0g);
        int S; float invS; substeps_for(p, S, invS);
        advance_interval<1>(ta, tb, e, S, invS, a, b);
        out[(size_t)(p + 1) * NE_ + ei] = make_float2(a[0], b[0]);
    }
}

extern "C" void kernel_launch(void* const* d_in, const int* in_sizes, int n_in,
                              void* d_out, int out_size, void* d_ws, size_t ws_size,
                              hipStream_t stream) {
    const float* evl = (const float*)d_in[0];   // NE_ energies
    const float* t   = (const float*)d_in[1];   // RN_ radial grid
    float2* out = (float2*)d_out;               // [RN_][NE_] of {rad, rad_d}

    const size_t needYst = (size_t)NCH_ * NE_ * sizeof(float2);   // 8 MB
    if (ws_size < needYst) {
        k_serial<<<(NE_ + 255) / 256, 256, 0, stream>>>(evl, t, out);
        return;
    }
    float2* Yst = (float2*)d_ws;

    // K1: 125 blocks x 512 threads (8 channels x 64 slots)
    k_scanfused<<<NE_ / CPB_, CPB_ * SLOTS_, 0, stream>>>(evl, t, Yst);
    // K2: 1M threads, proven coalesced writer
    const int ntask = NE_ * NCH_;
    k_out<<<(ntask + 255) / 256, 256, 0, stream>>>(evl, t, Yst, out);
}